// Round 1
// baseline (2821.543 us; speedup 1.0000x reference)
//
#include <hip/hip_runtime.h>
#include <cfloat>

#define NPTS   16384
#define MATOMS 8192
#define CH     16
#define ADIM   6
#define KNN    16
#define CHUNK  2048

__device__ __forceinline__ float leakyf(float x) { return x >= 0.0f ? x : 0.2f * x; }

// ---------------------------------------------------------------------------
// Kernel A: per-atom feature MLP t = L3(L2(L1(atomtypes))) + packed pos4
// ---------------------------------------------------------------------------
__global__ void __launch_bounds__(256) prep_kernel(
    const float* __restrict__ atom_xyz,
    const float* __restrict__ atomtypes,
    const int*   __restrict__ atom_batch,
    const float* __restrict__ Wt1, const float* __restrict__ bt1,
    const float* __restrict__ Wt2, const float* __restrict__ bt2,
    const float* __restrict__ Wt3, const float* __restrict__ bt3,
    float4* __restrict__ pos4,
    float*  __restrict__ tbuf,
    int*    __restrict__ abatch)
{
    __shared__ float w1[CH*ADIM], w2[CH*CH], w3[CH*CH], bb1[CH], bb2[CH], bb3[CH];
    const int tid = threadIdx.x;
    if (tid < CH*ADIM) w1[tid] = Wt1[tid];
    if (tid < CH*CH)   { w2[tid] = Wt2[tid]; w3[tid] = Wt3[tid]; }
    if (tid < CH)      { bb1[tid] = bt1[tid]; bb2[tid] = bt2[tid]; bb3[tid] = bt3[tid]; }
    __syncthreads();
    const int m = blockIdx.x * 256 + tid;
    if (m >= MATOMS) return;

    float x[ADIM];
    #pragma unroll
    for (int j = 0; j < ADIM; ++j) x[j] = atomtypes[m*ADIM + j];

    float h0[CH], h1[CH], h2[CH];
    #pragma unroll
    for (int c = 0; c < CH; ++c) {
        float a = 0.0f;
        #pragma unroll
        for (int j = 0; j < ADIM; ++j) a = fmaf(w1[c*ADIM+j], x[j], a);
        h0[c] = leakyf(a + bb1[c]);
    }
    #pragma unroll
    for (int c = 0; c < CH; ++c) {
        float a = 0.0f;
        #pragma unroll
        for (int j = 0; j < CH; ++j) a = fmaf(w2[c*CH+j], h0[j], a);
        h1[c] = leakyf(a + bb2[c]);
    }
    #pragma unroll
    for (int c = 0; c < CH; ++c) {
        float a = 0.0f;
        #pragma unroll
        for (int j = 0; j < CH; ++j) a = fmaf(w3[c*CH+j], h1[j], a);
        h2[c] = leakyf(a + bb3[c]);
    }
    #pragma unroll
    for (int c = 0; c < CH; ++c) tbuf[m*CH + c] = h2[c];

    const float ax = atom_xyz[m*3+0], ay = atom_xyz[m*3+1], az = atom_xyz[m*3+2];
    // np: sum(a*a, -1) = ((ax^2 + ay^2) + az^2), no FMA contraction
    const float a2 = __fadd_rn(__fadd_rn(__fmul_rn(ax,ax), __fmul_rn(ay,ay)), __fmul_rn(az,az));
    pos4[m] = make_float4(ax, ay, az, a2);
    abatch[m] = atom_batch[m];
}

// ---------------------------------------------------------------------------
// Kernel B: per-point brute-force 16-NN (np-matched d2 ordering) + feature
// contraction + output MLP, fused.  One thread per point.
// ---------------------------------------------------------------------------
__global__ void __launch_bounds__(256) atom_main_kernel(
    const float* __restrict__ xyz,
    const int*   __restrict__ batch,
    const float4* __restrict__ pos4,
    const float* __restrict__ tbuf,
    const int*   __restrict__ abatch,
    const float* __restrict__ Watt,
    const float* __restrict__ We1, const float* __restrict__ be1,
    const float* __restrict__ We2, const float* __restrict__ be2,
    const float* __restrict__ We3, const float* __restrict__ be3,
    float* __restrict__ out)
{
    __shared__ float4 lpos[CHUNK];
    __shared__ int    lbat[CHUNK];
    __shared__ float  lwatt[KNN];
    __shared__ float  lw1[CH*CH], lw2[CH*CH], lw3[CH*CH], lb1[CH], lb2[CH], lb3[CH];
    const int tid = threadIdx.x;
    lw1[tid] = We1[tid]; lw2[tid] = We2[tid]; lw3[tid] = We3[tid];
    if (tid < CH) { lb1[tid] = be1[tid]; lb2[tid] = be2[tid]; lb3[tid] = be3[tid]; lwatt[tid] = Watt[tid]; }

    const int n = blockIdx.x * 256 + tid;
    const float px = xyz[n*3+0], py = xyz[n*3+1], pz = xyz[n*3+2];
    // np: sum(x*x, -1) sequential, no FMA
    const float pn2 = __fadd_rn(__fadd_rn(__fmul_rn(px,px), __fmul_rn(py,py)), __fmul_rn(pz,pz));
    const int pb = batch[n];

    float bd[KNN]; int bi[KNN];
    #pragma unroll
    for (int j = 0; j < KNN; ++j) { bd[j] = FLT_MAX; bi[j] = 0x7fffffff; }

    for (int c0 = 0; c0 < MATOMS; c0 += CHUNK) {
        __syncthreads();
        for (int i = tid; i < CHUNK; i += 256) {
            lpos[i] = pos4[c0 + i];
            lbat[i] = abatch[c0 + i];
        }
        __syncthreads();
        for (int i = 0; i < CHUNK; ++i) {
            const float4 a = lpos[i];
            // np: d2 = (pn2 + a2) - 2*(x@aT);  BLAS dot = sequential FMA k=0,1,2
            const float dot = fmaf(pz, a.z, fmaf(py, a.y, __fmul_rn(px, a.x)));
            const float d2  = __fsub_rn(__fadd_rn(pn2, a.w), 2.0f * dot);
            // masked (batch mismatch) entries are d2=BIG in ref; skipping is
            // equivalent when >=K valid candidates exist (here: all valid).
            if (lbat[i] == pb && d2 < bd[KNN-1]) {
                float d = d2; int id = c0 + i;
                // lexicographic (d, idx) bubble insert -> matches lax.top_k
                // stable tie-break (lower index first) and handles duplicates.
                #pragma unroll
                for (int j = 0; j < KNN; ++j) {
                    const bool sw = (d < bd[j]) || (d == bd[j] && id < bi[j]);
                    const float od = bd[j]; const int oi = bi[j];
                    bd[j] = sw ? d  : bd[j];
                    bi[j] = sw ? id : bi[j];
                    d  = sw ? od : d;
                    id = sw ? oi : id;
                }
            }
        }
    }

    // ---- feature contraction: fx[c,d] = sum_k nv[k,d] * t[idx_k,c] * Watt[k]
    float acc[CH][3];
    #pragma unroll
    for (int c = 0; c < CH; ++c) { acc[c][0] = 0.0f; acc[c][1] = 0.0f; acc[c][2] = 0.0f; }

    #pragma unroll
    for (int k = 0; k < KNN; ++k) {
        const int j = bi[k];
        const float4 a = pos4[j];
        const float v0 = __fsub_rn(px, a.x);
        const float v1 = __fsub_rn(py, a.y);
        const float v2 = __fsub_rn(pz, a.z);
        // np: dists = sum(vecs*vecs, -1), sequential, no FMA (recomputed, != d2)
        const float dist = __fadd_rn(__fadd_rn(__fmul_rn(v0,v0), __fmul_rn(v1,v1)), __fmul_rn(v2,v2));
        const float w = 1.0f / __fadd_rn(dist, 1e-8f);   // power(x, -1.0)
        const float nv0 = __fmul_rn(v0, w);              // norm_vec explicit rounding
        const float nv1 = __fmul_rn(v1, w);
        const float nv2 = __fmul_rn(v2, w);
        const float wk = lwatt[k];
        const float4* tv = reinterpret_cast<const float4*>(tbuf + (size_t)j * CH);
        const float4 f0 = tv[0], f1 = tv[1], f2 = tv[2], f3 = tv[3];
        const float fc[CH] = {f0.x,f0.y,f0.z,f0.w, f1.x,f1.y,f1.z,f1.w,
                              f2.x,f2.y,f2.z,f2.w, f3.x,f3.y,f3.z,f3.w};
        #pragma unroll
        for (int c = 0; c < CH; ++c) {
            const float fw = __fmul_rn(fc[c], wk);
            acc[c][0] = fmaf(nv0, fw, acc[c][0]);
            acc[c][1] = fmaf(nv1, fw, acc[c][1]);
            acc[c][2] = fmaf(nv2, fw, acc[c][2]);
        }
    }

    float fx[CH];
    #pragma unroll
    for (int c = 0; c < CH; ++c) {
        const float s = __fadd_rn(__fadd_rn(__fmul_rn(acc[c][0], acc[c][0]),
                                            __fmul_rn(acc[c][1], acc[c][1])),
                                  __fmul_rn(acc[c][2], acc[c][2]));
        fx[c] = sqrtf(s);
    }

    float g1[CH], g2[CH];
    #pragma unroll
    for (int c = 0; c < CH; ++c) {
        float a = 0.0f;
        #pragma unroll
        for (int j2 = 0; j2 < CH; ++j2) a = fmaf(lw1[c*CH+j2], fx[j2], a);
        g1[c] = leakyf(a + lb1[c]);
    }
    #pragma unroll
    for (int c = 0; c < CH; ++c) {
        float a = 0.0f;
        #pragma unroll
        for (int j2 = 0; j2 < CH; ++j2) a = fmaf(lw2[c*CH+j2], g1[j2], a);
        g2[c] = leakyf(a + lb2[c]);
    }
    #pragma unroll
    for (int c = 0; c < CH; ++c) {
        float a = 0.0f;
        #pragma unroll
        for (int j2 = 0; j2 < CH; ++j2) a = fmaf(lw3[c*CH+j2], g2[j2], a);
        out[(size_t)n*CH + c] = a + lb3[c];
    }
}

// ---------------------------------------------------------------------------
extern "C" void kernel_launch(void* const* d_in, const int* in_sizes, int n_in,
                              void* d_out, int out_size, void* d_ws, size_t ws_size,
                              hipStream_t stream)
{
    (void)in_sizes; (void)n_in; (void)out_size; (void)ws_size;
    const float* xyz        = (const float*)d_in[0];
    const float* atom_xyz   = (const float*)d_in[1];
    const float* atomtypes  = (const float*)d_in[2];
    const int*   batch      = (const int*)d_in[3];
    const int*   atom_batch = (const int*)d_in[4];
    const float* Wt1 = (const float*)d_in[5];
    const float* bt1 = (const float*)d_in[6];
    const float* Wt2 = (const float*)d_in[7];
    const float* bt2 = (const float*)d_in[8];
    const float* Wt3 = (const float*)d_in[9];
    const float* bt3 = (const float*)d_in[10];
    const float* Watt = (const float*)d_in[11];
    const float* We1 = (const float*)d_in[12];
    const float* be1 = (const float*)d_in[13];
    const float* We2 = (const float*)d_in[14];
    const float* be2 = (const float*)d_in[15];
    const float* We3 = (const float*)d_in[16];
    const float* be3 = (const float*)d_in[17];

    char* ws = (char*)d_ws;
    float4* pos4  = (float4*)ws;                          // 8192*16  = 131072 B
    float*  tbuf  = (float*)(ws + 131072);                // 8192*64  = 524288 B
    int*    abat  = (int*)(ws + 131072 + 524288);         // 8192*4   =  32768 B
    float*  out   = (float*)d_out;

    hipLaunchKernelGGL(prep_kernel, dim3(MATOMS/256), dim3(256), 0, stream,
                       atom_xyz, atomtypes, atom_batch,
                       Wt1, bt1, Wt2, bt2, Wt3, bt3,
                       pos4, tbuf, abat);
    hipLaunchKernelGGL(atom_main_kernel, dim3(NPTS/256), dim3(256), 0, stream,
                       xyz, batch, pos4, tbuf, abat,
                       Watt, We1, be1, We2, be2, We3, be3,
                       out);
}

// Round 2
// 352.496 us; speedup vs baseline: 8.0045x; 8.0045x over previous
//
#include <hip/hip_runtime.h>
#include <cfloat>

#define NPTS   16384
#define MATOMS 8192
#define CH     16
#define ADIM   6
#define KNN    16
#define GROUPS_PER_BLOCK 16
#define BIGF   1e10f

__device__ __forceinline__ float leakyf(float x) { return x >= 0.0f ? x : 0.2f * x; }

// ---------------------------------------------------------------------------
// Kernel A: per-atom feature MLP t = L3(L2(L1(atomtypes))) + packed pos4
// ---------------------------------------------------------------------------
__global__ void __launch_bounds__(256) prep_kernel(
    const float* __restrict__ atom_xyz,
    const float* __restrict__ atomtypes,
    const int*   __restrict__ atom_batch,
    const float* __restrict__ Wt1, const float* __restrict__ bt1,
    const float* __restrict__ Wt2, const float* __restrict__ bt2,
    const float* __restrict__ Wt3, const float* __restrict__ bt3,
    float4* __restrict__ pos4,
    float*  __restrict__ tbuf,
    int*    __restrict__ abatch)
{
    __shared__ float w1[CH*ADIM], w2[CH*CH], w3[CH*CH], bb1[CH], bb2[CH], bb3[CH];
    const int tid = threadIdx.x;
    if (tid < CH*ADIM) w1[tid] = Wt1[tid];
    if (tid < CH*CH)   { w2[tid] = Wt2[tid]; w3[tid] = Wt3[tid]; }
    if (tid < CH)      { bb1[tid] = bt1[tid]; bb2[tid] = bt2[tid]; bb3[tid] = bt3[tid]; }
    __syncthreads();
    const int m = blockIdx.x * 256 + tid;
    if (m >= MATOMS) return;

    float x[ADIM];
    #pragma unroll
    for (int j = 0; j < ADIM; ++j) x[j] = atomtypes[m*ADIM + j];

    float h0[CH], h1[CH], h2[CH];
    #pragma unroll
    for (int c = 0; c < CH; ++c) {
        float a = 0.0f;
        #pragma unroll
        for (int j = 0; j < ADIM; ++j) a = fmaf(w1[c*ADIM+j], x[j], a);
        h0[c] = leakyf(a + bb1[c]);
    }
    #pragma unroll
    for (int c = 0; c < CH; ++c) {
        float a = 0.0f;
        #pragma unroll
        for (int j = 0; j < CH; ++j) a = fmaf(w2[c*CH+j], h0[j], a);
        h1[c] = leakyf(a + bb2[c]);
    }
    #pragma unroll
    for (int c = 0; c < CH; ++c) {
        float a = 0.0f;
        #pragma unroll
        for (int j = 0; j < CH; ++j) a = fmaf(w3[c*CH+j], h1[j], a);
        h2[c] = leakyf(a + bb3[c]);
    }
    #pragma unroll
    for (int c = 0; c < CH; ++c) tbuf[m*CH + c] = h2[c];

    const float ax = atom_xyz[m*3+0], ay = atom_xyz[m*3+1], az = atom_xyz[m*3+2];
    // np: sum(a*a, -1) = ((ax^2 + ay^2) + az^2), no FMA contraction
    const float a2 = __fadd_rn(__fadd_rn(__fmul_rn(ax,ax), __fmul_rn(ay,ay)), __fmul_rn(az,az));
    pos4[m] = make_float4(ax, ay, az, a2);
    abatch[m] = atom_batch[m];
}

// ---------------------------------------------------------------------------
// Kernel B: 16 lanes per point. Split-atom 16-NN scan + butterfly pop-min
// merge + per-channel contraction + shuffle-based output MLP.
// ---------------------------------------------------------------------------
__global__ void __launch_bounds__(256) atom_main_kernel(
    const float* __restrict__ xyz,
    const int*   __restrict__ batch,
    const float4* __restrict__ pos4,
    const float* __restrict__ tbuf,
    const int*   __restrict__ abatch,
    const float* __restrict__ Watt,
    const float* __restrict__ We1, const float* __restrict__ be1,
    const float* __restrict__ We2, const float* __restrict__ be2,
    const float* __restrict__ We3, const float* __restrict__ be3,
    float* __restrict__ out)
{
    // transposed weights: lwXt[j*16+c] = W[c][j]  -> conflict-free lane reads
    __shared__ float lw1t[CH*CH], lw2t[CH*CH], lw3t[CH*CH];
    __shared__ float lb1[CH], lb2[CH], lb3[CH], lwatt[KNN];
    const int tid = threadIdx.x;
    lw1t[tid] = We1[(tid & 15)*CH + (tid >> 4)];
    lw2t[tid] = We2[(tid & 15)*CH + (tid >> 4)];
    lw3t[tid] = We3[(tid & 15)*CH + (tid >> 4)];
    if (tid < CH) { lb1[tid] = be1[tid]; lb2[tid] = be2[tid]; lb3[tid] = be3[tid]; lwatt[tid] = Watt[tid]; }
    __syncthreads();

    const int c = tid & 15;                         // lane-in-group == channel
    const int n = blockIdx.x * GROUPS_PER_BLOCK + (tid >> 4);

    const float px = xyz[n*3+0], py = xyz[n*3+1], pz = xyz[n*3+2];
    // np: sum(x*x, -1) sequential, no FMA
    const float pn2 = __fadd_rn(__fadd_rn(__fmul_rn(px,px), __fmul_rn(py,py)), __fmul_rn(pz,pz));
    const int pb = batch[n];

    // ---- per-lane top-16 over atoms i = it*16 + c (increasing index order).
    // Strict '<' d-only compares are EXACT here: new candidates always have a
    // higher index than list members, so stable (d, idx) order is preserved.
    float bd[KNN]; int bi[KNN];
    #pragma unroll
    for (int j = 0; j < KNN; ++j) { bd[j] = FLT_MAX; bi[j] = 0x7fffffff; }

    for (int it = 0; it < MATOMS/16; ++it) {
        const int i = it*16 + c;
        const float4 a = pos4[i];
        const int ab = abatch[i];
        // np: d2 = (pn2 + a2) - 2*(x@aT); BLAS dot = sequential FMA k=0,1,2
        const float dot = fmaf(pz, a.z, fmaf(py, a.y, __fmul_rn(px, a.x)));
        float d2 = __fsub_rn(__fadd_rn(pn2, a.w), 2.0f * dot);
        d2 = (ab == pb) ? d2 : BIGF;                // reference mask semantics
        if (d2 < bd[KNN-1]) {
            float d = d2; int id = i;
            #pragma unroll
            for (int j = 0; j < KNN; ++j) {
                const bool sw = d < bd[j];
                const float od = bd[j]; const int oi = bi[j];
                bd[j] = sw ? d  : bd[j];
                bi[j] = sw ? id : bi[j];
                d  = sw ? od : d;
                id = sw ? oi : id;
            }
        }
    }

    // ---- merge 16 sorted lists: 16x pop-min via 16-lane butterfly with
    // lexicographic (d, idx) compare -> exact lax.top_k tie-break.
    int idxk[KNN];
    #pragma unroll
    for (int k = 0; k < KNN; ++k) {
        float d = bd[0]; int i = bi[0];
        #pragma unroll
        for (int m = 1; m <= 8; m <<= 1) {
            const float pd = __shfl_xor(d, m);
            const int   pi = __shfl_xor(i, m);
            const bool take = (pd < d) || (pd == d && pi < i);
            d = take ? pd : d;
            i = take ? pi : i;
        }
        idxk[k] = i;                                // all 16 lanes have winner
        const bool win = (bd[0] == d) && (bi[0] == i);
        if (win) {
            #pragma unroll
            for (int j = 0; j < KNN-1; ++j) { bd[j] = bd[j+1]; bi[j] = bi[j+1]; }
            bd[KNN-1] = FLT_MAX; bi[KNN-1] = 0x7fffffff;
        }
    }

    // ---- contraction: lane c accumulates channel c only.
    float ac0 = 0.0f, ac1 = 0.0f, ac2 = 0.0f;
    #pragma unroll
    for (int k = 0; k < KNN; ++k) {
        const int j = idxk[k];
        const float4 a = pos4[j];
        const float v0 = __fsub_rn(px, a.x);
        const float v1 = __fsub_rn(py, a.y);
        const float v2 = __fsub_rn(pz, a.z);
        // np: dists = sum(vecs*vecs, -1), sequential, no FMA (recomputed)
        const float dist = __fadd_rn(__fadd_rn(__fmul_rn(v0,v0), __fmul_rn(v1,v1)), __fmul_rn(v2,v2));
        const float w = 1.0f / __fadd_rn(dist, 1e-8f);   // power(x, -1.0)
        const float nv0 = __fmul_rn(v0, w);
        const float nv1 = __fmul_rn(v1, w);
        const float nv2 = __fmul_rn(v2, w);
        const float fc = tbuf[(size_t)j * CH + c];
        const float fw = __fmul_rn(fc, lwatt[k]);
        ac0 = fmaf(nv0, fw, ac0);
        ac1 = fmaf(nv1, fw, ac1);
        ac2 = fmaf(nv2, fw, ac2);
    }
    const float s = __fadd_rn(__fadd_rn(__fmul_rn(ac0,ac0), __fmul_rn(ac1,ac1)),
                              __fmul_rn(ac2,ac2));
    const float fx = sqrtf(s);

    // ---- output MLP: lane c computes channel c; fx values shared via shfl.
    float a1 = 0.0f;
    #pragma unroll
    for (int j = 0; j < CH; ++j) {
        const float fj = __shfl(fx, j, 16);
        a1 = fmaf(lw1t[j*CH + c], fj, a1);
    }
    const float g1 = leakyf(a1 + lb1[c]);

    float a2 = 0.0f;
    #pragma unroll
    for (int j = 0; j < CH; ++j) {
        const float gj = __shfl(g1, j, 16);
        a2 = fmaf(lw2t[j*CH + c], gj, a2);
    }
    const float g2 = leakyf(a2 + lb2[c]);

    float a3 = 0.0f;
    #pragma unroll
    for (int j = 0; j < CH; ++j) {
        const float gj = __shfl(g2, j, 16);
        a3 = fmaf(lw3t[j*CH + c], gj, a3);
    }
    out[(size_t)n*CH + c] = a3 + lb3[c];
}

// ---------------------------------------------------------------------------
extern "C" void kernel_launch(void* const* d_in, const int* in_sizes, int n_in,
                              void* d_out, int out_size, void* d_ws, size_t ws_size,
                              hipStream_t stream)
{
    (void)in_sizes; (void)n_in; (void)out_size; (void)ws_size;
    const float* xyz        = (const float*)d_in[0];
    const float* atom_xyz   = (const float*)d_in[1];
    const float* atomtypes  = (const float*)d_in[2];
    const int*   batch      = (const int*)d_in[3];
    const int*   atom_batch = (const int*)d_in[4];
    const float* Wt1 = (const float*)d_in[5];
    const float* bt1 = (const float*)d_in[6];
    const float* Wt2 = (const float*)d_in[7];
    const float* bt2 = (const float*)d_in[8];
    const float* Wt3 = (const float*)d_in[9];
    const float* bt3 = (const float*)d_in[10];
    const float* Watt = (const float*)d_in[11];
    const float* We1 = (const float*)d_in[12];
    const float* be1 = (const float*)d_in[13];
    const float* We2 = (const float*)d_in[14];
    const float* be2 = (const float*)d_in[15];
    const float* We3 = (const float*)d_in[16];
    const float* be3 = (const float*)d_in[17];

    char* ws = (char*)d_ws;
    float4* pos4  = (float4*)ws;                          // 8192*16  = 131072 B
    float*  tbuf  = (float*)(ws + 131072);                // 8192*64  = 524288 B
    int*    abat  = (int*)(ws + 131072 + 524288);         // 8192*4   =  32768 B
    float*  out   = (float*)d_out;

    hipLaunchKernelGGL(prep_kernel, dim3(MATOMS/256), dim3(256), 0, stream,
                       atom_xyz, atomtypes, atom_batch,
                       Wt1, bt1, Wt2, bt2, Wt3, bt3,
                       pos4, tbuf, abat);
    hipLaunchKernelGGL(atom_main_kernel, dim3(NPTS/GROUPS_PER_BLOCK), dim3(256), 0, stream,
                       xyz, batch, pos4, tbuf, abat,
                       Watt, We1, be1, We2, be2, We3, be3,
                       out);
}

// Round 4
// 199.608 us; speedup vs baseline: 14.1354x; 1.7659x over previous
//
#include <hip/hip_runtime.h>
#include <cfloat>

#define NPTS   16384
#define MATOMS 8192
#define CH     16
#define ADIM   6
#define KNN    16
#define GROUPS_PER_BLOCK 16
#define BIGF   1e10f
#define SLOTS  64          // per-lane LDS candidate capacity (E~8 with exact subset tau)

__device__ __forceinline__ float leakyf(float x) { return x >= 0.0f ? x : 0.2f * x; }

// ---------------------------------------------------------------------------
// Kernel A: per-atom feature MLP t = L3(L2(L1(atomtypes))) + packed pos4
// ---------------------------------------------------------------------------
__global__ void __launch_bounds__(256) prep_kernel(
    const float* __restrict__ atom_xyz,
    const float* __restrict__ atomtypes,
    const int*   __restrict__ atom_batch,
    const float* __restrict__ Wt1, const float* __restrict__ bt1,
    const float* __restrict__ Wt2, const float* __restrict__ bt2,
    const float* __restrict__ Wt3, const float* __restrict__ bt3,
    float4* __restrict__ pos4,
    float*  __restrict__ tbuf,
    int*    __restrict__ abatch)
{
    __shared__ float w1[CH*ADIM], w2[CH*CH], w3[CH*CH], bb1[CH], bb2[CH], bb3[CH];
    const int tid = threadIdx.x;
    if (tid < CH*ADIM) w1[tid] = Wt1[tid];
    if (tid < CH*CH)   { w2[tid] = Wt2[tid]; w3[tid] = Wt3[tid]; }
    if (tid < CH)      { bb1[tid] = bt1[tid]; bb2[tid] = bt2[tid]; bb3[tid] = bt3[tid]; }
    __syncthreads();
    const int m = blockIdx.x * 256 + tid;
    if (m >= MATOMS) return;

    float x[ADIM];
    #pragma unroll
    for (int j = 0; j < ADIM; ++j) x[j] = atomtypes[m*ADIM + j];

    float h0[CH], h1[CH], h2[CH];
    #pragma unroll
    for (int c = 0; c < CH; ++c) {
        float a = 0.0f;
        #pragma unroll
        for (int j = 0; j < ADIM; ++j) a = fmaf(w1[c*ADIM+j], x[j], a);
        h0[c] = leakyf(a + bb1[c]);
    }
    #pragma unroll
    for (int c = 0; c < CH; ++c) {
        float a = 0.0f;
        #pragma unroll
        for (int j = 0; j < CH; ++j) a = fmaf(w2[c*CH+j], h0[j], a);
        h1[c] = leakyf(a + bb2[c]);
    }
    #pragma unroll
    for (int c = 0; c < CH; ++c) {
        float a = 0.0f;
        #pragma unroll
        for (int j = 0; j < CH; ++j) a = fmaf(w3[c*CH+j], h1[j], a);
        h2[c] = leakyf(a + bb3[c]);
    }
    #pragma unroll
    for (int c = 0; c < CH; ++c) tbuf[m*CH + c] = h2[c];

    const float ax = atom_xyz[m*3+0], ay = atom_xyz[m*3+1], az = atom_xyz[m*3+2];
    // np: sum(a*a, -1) = ((ax^2 + ay^2) + az^2), no FMA contraction
    const float a2 = __fadd_rn(__fadd_rn(__fmul_rn(ax,ax), __fmul_rn(ay,ay)), __fmul_rn(az,az));
    pos4[m] = make_float4(ax, ay, az, a2);
    abatch[m] = atom_batch[m];
}

// ---------------------------------------------------------------------------
// Kernel B: 16 lanes per point.
//   Phase A: insert-scan over 1/8 subset (stale-tau pruned)
//   tau-merge: pop-min x16 across lanes -> tau = EXACT subset 16th-smallest
//   Phase B: lean full scan, append (d2 <= tau) idx to lane-private LDS
//   overflow guard: group-or(cnt > SLOTS) -> fall back to full insert-scan
//   Phase C: exact top-16 via validated insert + lexicographic pop-min merge
//   Epilogue: per-channel contraction + shuffle MLP (validated, unchanged)
// ---------------------------------------------------------------------------
__global__ void __launch_bounds__(256) atom_main_kernel(
    const float* __restrict__ xyz,
    const int*   __restrict__ batch,
    const float4* __restrict__ pos4,
    const float* __restrict__ tbuf,
    const int*   __restrict__ abatch,
    const float* __restrict__ Watt,
    const float* __restrict__ We1, const float* __restrict__ be1,
    const float* __restrict__ We2, const float* __restrict__ be2,
    const float* __restrict__ We3, const float* __restrict__ be3,
    float* __restrict__ out)
{
    // transposed weights: lwXt[j*16+c] = W[c][j]  -> conflict-free lane reads
    __shared__ float lw1t[CH*CH], lw2t[CH*CH], lw3t[CH*CH];
    __shared__ float lb1[CH], lb2[CH], lb3[CH], lwatt[KNN];
    // candidate buffer: [group][slot][lane] u16, lane-interleaved
    __shared__ unsigned short lbuf[GROUPS_PER_BLOCK * SLOTS * 16];
    const int tid = threadIdx.x;
    lw1t[tid] = We1[(tid & 15)*CH + (tid >> 4)];
    lw2t[tid] = We2[(tid & 15)*CH + (tid >> 4)];
    lw3t[tid] = We3[(tid & 15)*CH + (tid >> 4)];
    if (tid < CH) { lb1[tid] = be1[tid]; lb2[tid] = be2[tid]; lb3[tid] = be3[tid]; lwatt[tid] = Watt[tid]; }
    __syncthreads();

    const int c = tid & 15;                         // lane-in-group == channel
    const int g = tid >> 4;                         // group-in-block
    const int n = blockIdx.x * GROUPS_PER_BLOCK + g;

    const float px = xyz[n*3+0], py = xyz[n*3+1], pz = xyz[n*3+2];
    // np: sum(x*x, -1) sequential, no FMA
    const float pn2 = __fadd_rn(__fadd_rn(__fmul_rn(px,px), __fmul_rn(py,py)), __fmul_rn(pz,pz));
    const int pb = batch[n];

    float bd[KNN]; int bi[KNN];
    #pragma unroll
    for (int j = 0; j < KNN; ++j) { bd[j] = FLT_MAX; bi[j] = 0x7fffffff; }

    // ---- Phase A: 1/8 systematic subset (1024 atoms), validated insert-scan
    // with stale-tau pruning. Pruned candidates are provably outside the
    // subset top-16 (>=16 collected entries beat them), so the merge below
    // still yields the subset's EXACT 16 smallest.
    float tau = FLT_MAX;
    for (int t8 = 0; t8 < 8; ++t8) {
        {   // refresh stale tau (group min of 16th-best)
            float tt = bd[KNN-1];
            tt = fminf(tt, __shfl_xor(tt, 1));
            tt = fminf(tt, __shfl_xor(tt, 2));
            tt = fminf(tt, __shfl_xor(tt, 4));
            tt = fminf(tt, __shfl_xor(tt, 8));
            tau = tt;
        }
        #pragma unroll
        for (int u = 0; u < 8; ++u) {
            const int i = ((t8*8 + u)*16 + c) * 8;      // increasing per lane
            const float4 a = pos4[i];
            const int ab = abatch[i];
            // np: d2 = (pn2 + a2) - 2*(x@aT); BLAS dot = sequential FMA
            const float dot = fmaf(pz, a.z, fmaf(py, a.y, __fmul_rn(px, a.x)));
            float d2 = __fsub_rn(__fadd_rn(pn2, a.w), 2.0f * dot);
            d2 = (ab == pb) ? d2 : BIGF;
            if (d2 < bd[KNN-1] && d2 <= tau) {
                float d = d2; int id = i;
                #pragma unroll
                for (int j = 0; j < KNN; ++j) {
                    const bool sw = d < bd[j];
                    const float od = bd[j]; const int oi = bi[j];
                    bd[j] = sw ? d  : bd[j];
                    bi[j] = sw ? id : bi[j];
                    d  = sw ? od : d;
                    id = sw ? oi : id;
                }
            }
        }
    }

    // ---- tau-merge: 16 pop-mins across the group -> tau = exact subset
    // 16th-smallest distance (last = largest popped). Consumes bd/bi.
    #pragma unroll
    for (int k = 0; k < KNN; ++k) {
        float d = bd[0]; int i = bi[0];
        #pragma unroll
        for (int m = 1; m <= 8; m <<= 1) {
            const float pd = __shfl_xor(d, m);
            const int   pi = __shfl_xor(i, m);
            const bool take = (pd < d) || (pd == d && pi < i);
            d = take ? pd : d;
            i = take ? pi : i;
        }
        tau = d;
        const bool win = (bd[0] == d) && (bi[0] == i);
        if (win) {
            #pragma unroll
            for (int j = 0; j < KNN-1; ++j) { bd[j] = bd[j+1]; bi[j] = bi[j+1]; }
            bd[KNN-1] = FLT_MAX; bi[KNN-1] = 0x7fffffff;
        }
    }

    // ---- Phase B: lean full scan; append qualifying idx (increasing order).
    int cnt = 0;
    unsigned short* seg = &lbuf[g * (SLOTS*16) + c];
    for (int t = 0; t < MATOMS/16; ++t) {
        const int i = t*16 + c;
        const float4 a = pos4[i];
        const int ab = abatch[i];
        const float dot = fmaf(pz, a.z, fmaf(py, a.y, __fmul_rn(px, a.x)));
        const float d2 = __fsub_rn(__fadd_rn(pn2, a.w), 2.0f * dot);
        if ((ab == pb) && (d2 <= tau)) {
            if (cnt < SLOTS) seg[cnt*16] = (unsigned short)i;
            ++cnt;
        }
    }

    // ---- overflow guard: group-or; fallback = validated full insert-scan.
    int ovf = (cnt > SLOTS) ? 1 : 0;
    ovf |= __shfl_xor(ovf, 1);
    ovf |= __shfl_xor(ovf, 2);
    ovf |= __shfl_xor(ovf, 4);
    ovf |= __shfl_xor(ovf, 8);

    #pragma unroll
    for (int j = 0; j < KNN; ++j) { bd[j] = FLT_MAX; bi[j] = 0x7fffffff; }

    if (ovf) {
        // round-2 validated path (rare; group-uniform)
        for (int t = 0; t < MATOMS/16; ++t) {
            const int i = t*16 + c;
            const float4 a = pos4[i];
            const int ab = abatch[i];
            const float dot = fmaf(pz, a.z, fmaf(py, a.y, __fmul_rn(px, a.x)));
            float d2 = __fsub_rn(__fadd_rn(pn2, a.w), 2.0f * dot);
            d2 = (ab == pb) ? d2 : BIGF;
            if (d2 < bd[KNN-1]) {
                float d = d2; int id = i;
                #pragma unroll
                for (int j = 0; j < KNN; ++j) {
                    const bool sw = d < bd[j];
                    const float od = bd[j]; const int oi = bi[j];
                    bd[j] = sw ? d  : bd[j];
                    bi[j] = sw ? id : bi[j];
                    d  = sw ? od : d;
                    id = sw ? oi : id;
                }
            }
        }
    } else {
        // ---- Phase C: exact top-16 of collected (appends were increasing-
        // index, so strict '<' d-only insert is tie-exact).
        for (int s = 0; s < cnt; ++s) {
            const int i = (int)seg[s*16];
            const float4 a = pos4[i];
            const float dot = fmaf(pz, a.z, fmaf(py, a.y, __fmul_rn(px, a.x)));
            const float d2 = __fsub_rn(__fadd_rn(pn2, a.w), 2.0f * dot);
            if (d2 < bd[KNN-1]) {
                float d = d2; int id = i;
                #pragma unroll
                for (int j = 0; j < KNN; ++j) {
                    const bool sw = d < bd[j];
                    const float od = bd[j]; const int oi = bi[j];
                    bd[j] = sw ? d  : bd[j];
                    bi[j] = sw ? id : bi[j];
                    d  = sw ? od : d;
                    id = sw ? oi : id;
                }
            }
        }
    }

    // ---- final merge: 16x pop-min, lexicographic (d, idx)
    int idxk[KNN];
    #pragma unroll
    for (int k = 0; k < KNN; ++k) {
        float d = bd[0]; int i = bi[0];
        #pragma unroll
        for (int m = 1; m <= 8; m <<= 1) {
            const float pd = __shfl_xor(d, m);
            const int   pi = __shfl_xor(i, m);
            const bool take = (pd < d) || (pd == d && pi < i);
            d = take ? pd : d;
            i = take ? pi : i;
        }
        idxk[k] = i;
        const bool win = (bd[0] == d) && (bi[0] == i);
        if (win) {
            #pragma unroll
            for (int j = 0; j < KNN-1; ++j) { bd[j] = bd[j+1]; bi[j] = bi[j+1]; }
            bd[KNN-1] = FLT_MAX; bi[KNN-1] = 0x7fffffff;
        }
    }

    // ---- contraction: lane c accumulates channel c only.
    float ac0 = 0.0f, ac1 = 0.0f, ac2 = 0.0f;
    #pragma unroll
    for (int k = 0; k < KNN; ++k) {
        const int j = idxk[k];
        const float4 a = pos4[j];
        const float v0 = __fsub_rn(px, a.x);
        const float v1 = __fsub_rn(py, a.y);
        const float v2 = __fsub_rn(pz, a.z);
        // np: dists = sum(vecs*vecs, -1), sequential, no FMA (recomputed)
        const float dist = __fadd_rn(__fadd_rn(__fmul_rn(v0,v0), __fmul_rn(v1,v1)), __fmul_rn(v2,v2));
        const float w = 1.0f / __fadd_rn(dist, 1e-8f);   // power(x, -1.0)
        const float nv0 = __fmul_rn(v0, w);
        const float nv1 = __fmul_rn(v1, w);
        const float nv2 = __fmul_rn(v2, w);
        const float fc = tbuf[(size_t)j * CH + c];
        const float fw = __fmul_rn(fc, lwatt[k]);
        ac0 = fmaf(nv0, fw, ac0);
        ac1 = fmaf(nv1, fw, ac1);
        ac2 = fmaf(nv2, fw, ac2);
    }
    const float s = __fadd_rn(__fadd_rn(__fmul_rn(ac0,ac0), __fmul_rn(ac1,ac1)),
                              __fmul_rn(ac2,ac2));
    const float fx = sqrtf(s);

    // ---- output MLP: lane c computes channel c; values shared via shfl.
    float a1 = 0.0f;
    #pragma unroll
    for (int j = 0; j < CH; ++j) {
        const float fj = __shfl(fx, j, 16);
        a1 = fmaf(lw1t[j*CH + c], fj, a1);
    }
    const float g1 = leakyf(a1 + lb1[c]);

    float a2 = 0.0f;
    #pragma unroll
    for (int j = 0; j < CH; ++j) {
        const float gj = __shfl(g1, j, 16);
        a2 = fmaf(lw2t[j*CH + c], gj, a2);
    }
    const float g2 = leakyf(a2 + lb2[c]);

    float a3 = 0.0f;
    #pragma unroll
    for (int j = 0; j < CH; ++j) {
        const float gj = __shfl(g2, j, 16);
        a3 = fmaf(lw3t[j*CH + c], gj, a3);
    }
    out[(size_t)n*CH + c] = a3 + lb3[c];
}

// ---------------------------------------------------------------------------
extern "C" void kernel_launch(void* const* d_in, const int* in_sizes, int n_in,
                              void* d_out, int out_size, void* d_ws, size_t ws_size,
                              hipStream_t stream)
{
    (void)in_sizes; (void)n_in; (void)out_size; (void)ws_size;
    const float* xyz        = (const float*)d_in[0];
    const float* atom_xyz   = (const float*)d_in[1];
    const float* atomtypes  = (const float*)d_in[2];
    const int*   batch      = (const int*)d_in[3];
    const int*   atom_batch = (const int*)d_in[4];
    const float* Wt1 = (const float*)d_in[5];
    const float* bt1 = (const float*)d_in[6];
    const float* Wt2 = (const float*)d_in[7];
    const float* bt2 = (const float*)d_in[8];
    const float* Wt3 = (const float*)d_in[9];
    const float* bt3 = (const float*)d_in[10];
    const float* Watt = (const float*)d_in[11];
    const float* We1 = (const float*)d_in[12];
    const float* be1 = (const float*)d_in[13];
    const float* We2 = (const float*)d_in[14];
    const float* be2 = (const float*)d_in[15];
    const float* We3 = (const float*)d_in[16];
    const float* be3 = (const float*)d_in[17];

    char* ws = (char*)d_ws;
    float4* pos4  = (float4*)ws;                          // 8192*16  = 131072 B
    float*  tbuf  = (float*)(ws + 131072);                // 8192*64  = 524288 B
    int*    abat  = (int*)(ws + 131072 + 524288);         // 8192*4   =  32768 B
    float*  out   = (float*)d_out;

    hipLaunchKernelGGL(prep_kernel, dim3(MATOMS/256), dim3(256), 0, stream,
                       atom_xyz, atomtypes, atom_batch,
                       Wt1, bt1, Wt2, bt2, Wt3, bt3,
                       pos4, tbuf, abat);
    hipLaunchKernelGGL(atom_main_kernel, dim3(NPTS/GROUPS_PER_BLOCK), dim3(256), 0, stream,
                       xyz, batch, pos4, tbuf, abat,
                       Watt, We1, be1, We2, be2, We3, be3,
                       out);
}